// Round 14
// baseline (187.503 us; speedup 1.0000x reference)
//
#include <hip/hip_runtime.h>
#include <math.h>

#define S 1024
#define RADIUS 512
#define NIMG 32   // 16 "output" images then 16 "target" images
#define PBX 129   // pass-B blocks per image (u-groups of 4)

// ---------------------------------------------------------------------------
// Complex helpers
// ---------------------------------------------------------------------------
__device__ __forceinline__ float2 cmul(float2 a, float2 b) {
    return make_float2(a.x * b.x - a.y * b.y, a.x * b.y + a.y * b.x);
}
__device__ __forceinline__ float2 cadd(float2 a, float2 b) { return make_float2(a.x + b.x, a.y + b.y); }
__device__ __forceinline__ float2 csub(float2 a, float2 b) { return make_float2(a.x - b.x, a.y - b.y); }

// W_16^k, k=0..7
__device__ const float2 C16[8] = {
    {1.0f, 0.0f},
    {0.92387953251128674f, -0.38268343236508978f},
    {0.70710678118654757f, -0.70710678118654746f},
    {0.38268343236508984f, -0.92387953251128674f},
    {0.0f, -1.0f},
    {-0.38268343236508973f, -0.92387953251128674f},
    {-0.70710678118654746f, -0.70710678118654757f},
    {-0.92387953251128663f, -0.38268343236508989f},
};
// W_8^k, k=0..3
__device__ const float2 C8T[4] = {
    {1.0f, 0.0f},
    {0.70710678118654757f, -0.70710678118654746f},
    {0.0f, -1.0f},
    {-0.70710678118654746f, -0.70710678118654757f},
};
// W512^m, m=0..7
__device__ const float2 W512T[8] = {
    {1.0f, 0.0f},
    {0.99992470183914454f, -0.012271538285719925f},
    {0.99969881869620425f, -0.024541228522912288f},
    {0.99932238458834954f, -0.036807222941358832f},
    {0.99879545620517241f, -0.049067674327418015f},
    {0.99811811290014918f, -0.061320736302208578f},
    {0.99729045667869021f, -0.073564563599667426f},
    {0.99631261218277800f, -0.085797312344439894f},
};
// W64^k, k=0..7
__device__ const float2 W64T[8] = {
    {1.0f, 0.0f},
    {0.99518472667219693f, -0.098017140329560604f},
    {0.98078528040323044f, -0.19509032201612825f},
    {0.95694033573220886f, -0.29028467725446233f},
    {0.92387953251128674f, -0.38268343236508978f},
    {0.88192126434835505f, -0.47139673682599764f},
    {0.83146961230254524f, -0.55557023301960218f},
    {0.77301045336273699f, -0.63439328416364549f},
};
// W128^h (plain order), h=0..7
__device__ const float2 W128P[8] = {
    {1.0f, 0.0f},
    {0.99879545620517241f, -0.049067674327418015f},
    {0.99518472667219693f, -0.098017140329560604f},
    {0.98917650996478101f, -0.14673047445536175f},
    {0.98078528040323044f, -0.19509032201612825f},
    {0.97003125319454397f, -0.24298017990326390f},
    {0.95694033573220886f, -0.29028467725446233f},
    {0.94154406518302081f, -0.33688985339222005f},
};
// W1024^l (plain order), l=0..7
__device__ const float2 W1024P[8] = {
    {1.0f, 0.0f},
    {0.99998117528260111f, -0.0061358846491544753f},
    {0.99992470183914454f, -0.012271538285719925f},
    {0.99983058179582340f, -0.018406729905804820f},
    {0.99969881869620425f, -0.024541228522912288f},
    {0.99952941750109314f, -0.030674803176636626f},
    {0.99932238458834954f, -0.036807222941358832f},
    {0.99907772775264536f, -0.042938256934940820f},
};

// 4 radix-2 DIF stages over 16 register elements (pass A)
__device__ __forceinline__ void fft16(float2 r[16], float2 T) {
    float2 tc[8];
    #pragma unroll
    for (int u = 0; u < 8; ++u) tc[u] = cmul(T, C16[u]);
    #pragma unroll
    for (int u = 0; u < 8; ++u) {
        float2 a = r[u], b = r[u + 8];
        r[u] = cadd(a, b);
        r[u + 8] = cmul(csub(a, b), tc[u]);
    }
    T = cmul(T, T);
    #pragma unroll
    for (int u = 0; u < 4; ++u) tc[u] = cmul(T, C16[2 * u]);
    #pragma unroll
    for (int g = 0; g < 2; ++g)
        #pragma unroll
        for (int u = 0; u < 4; ++u) {
            int lo = g * 8 + u;
            float2 a = r[lo], b = r[lo + 4];
            r[lo] = cadd(a, b);
            r[lo + 4] = cmul(csub(a, b), tc[u]);
        }
    T = cmul(T, T);
    #pragma unroll
    for (int u = 0; u < 2; ++u) tc[u] = cmul(T, C16[4 * u]);
    #pragma unroll
    for (int g = 0; g < 4; ++g)
        #pragma unroll
        for (int u = 0; u < 2; ++u) {
            int lo = g * 4 + u;
            float2 a = r[lo], b = r[lo + 2];
            r[lo] = cadd(a, b);
            r[lo + 2] = cmul(csub(a, b), tc[u]);
        }
    T = cmul(T, T);
    #pragma unroll
    for (int g = 0; g < 8; ++g) {
        int lo = g * 2;
        float2 a = r[lo], b = r[lo + 1];
        r[lo] = cadd(a, b);
        r[lo + 1] = cmul(csub(a, b), T);
    }
}

// 3 radix-2 DIF stages over 8 register elements
__device__ __forceinline__ void fft8(float2 r[8], float2 T) {
    float2 tc[4];
    #pragma unroll
    for (int u = 0; u < 4; ++u) tc[u] = cmul(T, C8T[u]);
    #pragma unroll
    for (int u = 0; u < 4; ++u) {
        float2 a = r[u], b = r[u + 4];
        r[u] = cadd(a, b);
        r[u + 4] = cmul(csub(a, b), tc[u]);
    }
    T = cmul(T, T);
    #pragma unroll
    for (int u = 0; u < 2; ++u) tc[u] = cmul(T, C8T[2 * u]);
    #pragma unroll
    for (int g = 0; g < 2; ++g)
        #pragma unroll
        for (int u = 0; u < 2; ++u) {
            int lo = g * 4 + u;
            float2 a = r[lo], b = r[lo + 2];
            r[lo] = cadd(a, b);
            r[lo + 2] = cmul(csub(a, b), tc[u]);
        }
    T = cmul(T, T);
    #pragma unroll
    for (int g = 0; g < 4; ++g) {
        int lo = g * 2;
        float2 a = r[lo], b = r[lo + 1];
        r[lo] = cadd(a, b);
        r[lo + 1] = cmul(csub(a, b), T);
    }
}

// Last 2 DIF stages (1024-pt, pass A): quad-perm shuffles across c = tau&3
__device__ __forceinline__ void fft_last2(float2 r[16], int c) {
    #pragma unroll
    for (int m = 0; m < 16; ++m) {
        float vx = __shfl_xor(r[m].x, 2, 64);
        float vy = __shfl_xor(r[m].y, 2, 64);
        if (c & 2) {
            float dx = vx - r[m].x, dy = vy - r[m].y;
            if (c & 1) { r[m].x = dy; r[m].y = -dx; }
            else       { r[m].x = dx; r[m].y = dy; }
        } else {
            r[m].x += vx; r[m].y += vy;
        }
    }
    #pragma unroll
    for (int m = 0; m < 16; ++m) {
        float vx = __shfl_xor(r[m].x, 1, 64);
        float vy = __shfl_xor(r[m].y, 1, 64);
        if (c & 1) { r[m].x = vx - r[m].x; r[m].y = vy - r[m].y; }
        else       { r[m].x += vx; r[m].y += vy; }
    }
}

__device__ __forceinline__ int bitrev3(int x) {
    return ((x & 1) << 2) | (x & 2) | ((x >> 2) & 1);
}

// ---------------------------------------------------------------------------
// Pass A (ROUND 14): DE-LOCKSTEP. Same validated math as R13, but 256-thread /
// 4-wave blocks (grid 128 x c), 16 KB LDS. Rationale: R11-R13 showed fft_rows
// pinned at ~90 us with VALU/DS/VMEM each ~30% and dur invariant to L3-vs-HBM
// input -> pipes behave sum-like (phase lockstep of 8-wave barrier blocks).
// 8 independent 4-wave blocks/CU give the CU phase-offset work so pipes can
// overlap across blocks. Staging tile [512][4] -> 32 B/uu stores (two blocks
// share a 64 B line; L2 merges). Falsifier: WRITE_SIZE inflation.
// ---------------------------------------------------------------------------
__global__ __launch_bounds__(256, 4)
void fft_rows(const float* __restrict__ outp, const float* __restrict__ tgtp,
              float2* __restrict__ WpT, int imgBase) {
    __shared__ float2 buf[2048];   // 16 KB: 4 x 512-slot wave regions / staging
    const int t = threadIdx.x;
    const int w = t >> 6, tau = t & 63;
    const int yy = blockIdx.x * 4 + w;
    const int i = blockIdx.y, g = imgBase + i;
    const float* img = (g < 16 ? outp : tgtp) + (size_t)(g & 15) * S * S;
    const float* r0 = img + (size_t)(2 * yy) * S;
    const float* r1 = r0 + S;

    float2* wb = buf + (w << 9);
    float* wf = (float*)wb;        // 1024 floats, wave-private

    float2 r[16];
    // row0: float4 loads -> LDS bounce -> r[].x  (same-wave DS ordering)
    #pragma unroll
    for (int q = 0; q < 4; ++q) {
        float4 v = *reinterpret_cast<const float4*>(&r0[q * 256 + 4 * tau]);
        *reinterpret_cast<float4*>(&wf[q * 256 + 4 * tau]) = v;
    }
    #pragma unroll
    for (int j = 0; j < 16; ++j) r[j].x = wf[64 * j + tau];
    // row1
    #pragma unroll
    for (int q = 0; q < 4; ++q) {
        float4 v = *reinterpret_cast<const float4*>(&r1[q * 256 + 4 * tau]);
        *reinterpret_cast<float4*>(&wf[q * 256 + 4 * tau]) = v;
    }
    #pragma unroll
    for (int j = 0; j < 16; ++j) r[j].y = wf[64 * j + tau];

    // T = W1024^tau (table product)
    fft16(r, cmul(W128P[tau >> 3], W1024P[tau & 7]));

    // ---- two-phase mid-transpose, wave-private 512-slot region (R12) ----
    const int b = tau >> 2, c = tau & 3;
    float2 ex[8];
    #pragma unroll
    for (int j = 0; j < 8; ++j) wb[(j << 6) | (tau ^ (j << 2))] = r[j];
    if (b < 8) {
        #pragma unroll
        for (int m = 0; m < 8; ++m)  r[m]      = wb[((b & 7) << 6) + 4 * ((m ^ b) & 15) + c];
        #pragma unroll
        for (int m = 8; m < 16; ++m) ex[m - 8] = wb[((b & 7) << 6) + 4 * ((m ^ b) & 15) + c];
    }
    #pragma unroll
    for (int j = 8; j < 16; ++j) wb[((j & 7) << 6) | (tau ^ (j << 2))] = r[j];
    if (b >= 8) {
        #pragma unroll
        for (int m = 0; m < 8; ++m)  r[m]      = wb[((b & 7) << 6) + 4 * ((m ^ b) & 15) + c];
        #pragma unroll
        for (int m = 8; m < 16; ++m) ex[m - 8] = wb[((b & 7) << 6) + 4 * ((m ^ b) & 15) + c];
    }
    #pragma unroll
    for (int m = 8; m < 16; ++m) r[m] = ex[m - 8];

    fft16(r, W64T[c]);          // T = W64^c
    fft_last2(r, c);

    // ---- two-phase output staging + float4 coalesced store ----
    const int yy0 = blockIdx.x * 4;
    float2* dst = WpT + (size_t)i * 512 * 1024;
    #pragma unroll
    for (int h = 0; h < 2; ++h) {
        if ((c & 1) == h) {                      // this half's 32 lanes own k-half h
            #pragma unroll
            for (int m = 0; m < 16; ++m) {
                int n = (b << 6) + 4 * m + c;
                int kh = (int)(__brev((unsigned)n) >> 22) & 511;
                buf[(w << 9) | (kh ^ (w << 1))] = r[m];   // own wave region
            }
        }
        __syncthreads();
        #pragma unroll
        for (int q = 0; q < 4; ++q) {
            int idx4 = q * 256 + t;              // 0..1023 = 512 uu x 2 pairs
            int p2 = (idx4 & 1) << 1;            // wv pair base: 0,2
            int uu = idx4 >> 1;                  // 0..511
            float2 v0 = buf[((p2 + 0) << 9) | (uu ^ ((p2 + 0) << 1))];
            float2 v1 = buf[((p2 + 1) << 9) | (uu ^ ((p2 + 1) << 1))];
            float4 vv = make_float4(v0.x, v0.y, v1.x, v1.y);
            *reinterpret_cast<float4*>(&dst[(size_t)(uu + (h << 9)) * 512 + yy0 + p2]) = vv;
        }
        __syncthreads();
    }
}

// ---------------------------------------------------------------------------
// Pass B (unchanged — validated R13): split-wave FFT + combine + PER-WAVE
// scan binning (5 barriers, zero atomics).
// ---------------------------------------------------------------------------
__global__ __launch_bounds__(512, 4)
void fft_cols_bin2(const float2* __restrict__ WpT, float* __restrict__ partial, int imgBase) {
    __shared__ float2 tbuf[8 * 512];      // 32 KB, multi-phase aliased
    const int t = threadIdx.x;
    const int w = t >> 6, tau = t & 63;
    const int i = blockIdx.y, g = imgBase + i;
    const int l = w >> 1;                 // local u index 0..3
    const int u = blockIdx.x * 4 + l;     // 0..515
    const int setb = w & 1;               // 0: X0 FFT (v=f), 1: X1 FFT (v=f+512)
    const bool active = (u <= 512);

    const int b3 = tau >> 3, lam = tau & 7;
    float2 X[8];
    float2* mb = tbuf + (w << 9);

    if (active) {
        const float2* Wimg = WpT + (size_t)i * 512 * 1024;
        const int mu = (1024 - u) & 1023;
        const float2* rowA = Wimg + (size_t)u * 512;
        const float2* rowM = Wimg + (size_t)mu * 512;

        #pragma unroll
        for (int j = 0; j < 8; ++j) {
            float2 A = rowA[64 * j + tau];
            float2 M = rowM[64 * j + tau];
            X[j] = (setb == 0)
                 ? make_float2(0.5f * (A.x + M.x), 0.5f * (A.y - M.y))
                 : make_float2(0.5f * (A.y + M.y), 0.5f * (M.x - A.x));
        }

        // Phase 1; T = W512^tau = W64^{b3} * W512^{lam}
        fft8(X, cmul(W64T[b3], W512T[lam]));

        // Transpose 1 (wave-private, swizzled, conflict-free)
        #pragma unroll
        for (int j = 0; j < 8; ++j) mb[(j << 6) | (tau ^ (j << 3) ^ j)] = X[j];
        #pragma unroll
        for (int c = 0; c < 8; ++c) X[c] = mb[(b3 << 6) | (((c ^ b3) << 3) | (lam ^ b3))];

        // Phase 2; T = W64^{lam}
        fft8(X, W64T[lam]);

        // Transpose 2
        #pragma unroll
        for (int c = 0; c < 8; ++c) mb[(b3 << 6) | (((c ^ b3) << 3) | (lam ^ b3))] = X[c];
        #pragma unroll
        for (int d = 0; d < 8; ++d) X[d] = mb[(b3 << 6) | (((lam ^ b3) << 3) | (d ^ b3))];

        // Phase 3 (T = 1)
        fft8(X, make_float2(1.0f, 0.0f));

        // Publish in NATURAL-f order: X[d] is freq f = 64*rev3(d)+8*rev3(lam)+rev3(b3)
        const int base9 = 8 * bitrev3(lam) + bitrev3(b3);
        #pragma unroll
        for (int d = 0; d < 8; ++d) {
            mb[(bitrev3(d) << 6) + base9] = X[d];
        }
    }
    __syncthreads();   // (1) cross-wave spectra exchange

    float p[8];
    if (active) {
        const float2* b0 = tbuf + ((w & ~1) << 9);   // X0-hat, natural-f
        const float2* b1 = tbuf + ((w | 1) << 9);    // X1-hat, natural-f
        const float2 Wtau = cmul(W128P[tau >> 3], W1024P[tau & 7]);  // W1024^tau
        #pragma unroll
        for (int m = 0; m < 8; ++m) {
            const int f = tau + 64 * m;
            float2 x0 = b0[f];
            float2 x1 = b1[f];
            float2 Wf = cmul(Wtau, C16[m]);          // W1024^f
            float2 wx = cmul(Wf, x1);
            float2 G = (setb == 0) ? cadd(x0, wx)    // v = f
                                   : csub(x0, wx);   // v = f + 512
            p[m] = G.x * G.x + G.y * G.y;
        }
    }
    __syncthreads();   // (2) spectra reads done -> safe to alias Prow

    float* Prow = (float*)tbuf;                      // floats [0..4095] = [4][1024]
    float* wpref = ((float*)tbuf) + 4096;            // floats [4096..8191] = [8][512]
    if (active) {
        #pragma unroll
        for (int m = 0; m < 8; ++m) {
            const int v = tau + 64 * m + (setb << 9);
            Prow[(l << 10) + v] = p[m];
        }
    }
    __syncthreads();   // (3) Prow ready

    // ---- per-wave scan + ring windows: wave w owns row (l = w>>1, mir = w&1) ----
    const int mir = w & 1;
    const int uu = blockIdx.x * 4 + l;
    const bool valid = (uu <= 512) && (!mir || (uu >= 1 && uu <= 511));
    const float* PR = Prow + (l << 10);
    float* myp = wpref + (w << 9);

    float carry = 0.0f;
    #pragma unroll
    for (int k = 0; k < 8; ++k) {
        const int idx = (k << 6) + tau;
        float F = 0.0f;
        if (valid) {
            F = mir ? (PR[idx + 1] + PR[(1024 - idx) & 1023])   // mirror row
                    : (PR[idx] + PR[1023 - idx]);               // direct fold
        }
        float s = F;
        #pragma unroll
        for (int off = 1; off < 64; off <<= 1) {
            float n = __shfl_up(s, off, 64);
            if (tau >= off) s += n;
        }
        myp[idx] = s + carry;                 // inclusive prefix over 512
        carry += __shfl(s, 63, 64);           // chunk total
    }
    // window lookups: thread tau resolves rings r = tau + 64m from OWN prefix
    const float cuv = mir ? ((float)uu - 0.5f)
                          : ((uu < 512) ? ((float)uu + 0.5f) : 511.5f);
    const float cu2 = cuv * cuv;              // exact in f32
    float acc[8];
    #pragma unroll
    for (int m = 0; m < 8; ++m) {
        acc[m] = 0.0f;
        if (valid) {
            const int r = tau + (m << 6);
            const float r2  = (float)(r * r);
            const float r12 = (float)((r + 1) * (r + 1));
            const float Bv = r12 - cu2;       // exact
            if (Bv > 0.0f) {
                const float Av = r2 - cu2;    // exact
                float cvlo = (Av > 0.0f) ? sqrtf(Av) : 0.0f;
                float cvhi = sqrtf(Bv);
                int vlo = (int)ceilf(cvlo - 0.5f);
                int vhi = (int)ceilf(cvhi - 0.5f);
                if (vhi > 512) vhi = 512;
                if (vlo < 0) vlo = 0;
                if (vhi > vlo) {
                    float hi = myp[vhi - 1];
                    float lo = (vlo > 0) ? myp[vlo - 1] : 0.0f;
                    acc[m] = hi - lo;
                }
            }
        }
    }
    __syncthreads();   // (4) all waves done with Prow/wpref reads

    float* wavebins = (float*)tbuf;           // floats [0..4095] = [8][512]
    #pragma unroll
    for (int m = 0; m < 8; ++m) {
        wavebins[(w << 9) + (m << 6) + tau] = acc[m];
    }
    __syncthreads();   // (5) wavebins ready

    float sum = 0.0f;
    #pragma unroll
    for (int ww = 0; ww < 8; ++ww) sum += wavebins[(ww << 9) + t];
    // per-block partial; every slot written every call (re-poison safe)
    partial[(((size_t)g * PBX) + blockIdx.x) * 512 + t] = sum;
}

// ---------------------------------------------------------------------------
// Fold partials -> rad  (block per image, 129 block-partials)
// ---------------------------------------------------------------------------
__global__ __launch_bounds__(512)
void reduce_partials(const float* __restrict__ partial, float* __restrict__ rad) {
    const int g = blockIdx.x;
    const int t = threadIdx.x;
    const float* p = partial + (size_t)g * PBX * 512;
    float s = 0.0f;
    for (int b = 0; b < PBX; ++b) s += p[(size_t)b * 512 + t];
    rad[(size_t)g * 512 + t] = s;
}

// ---------------------------------------------------------------------------
// Final: loss = mean(|rad_out - rad_tgt|) / S^2
// ---------------------------------------------------------------------------
__global__ __launch_bounds__(256)
void final_loss(const float* __restrict__ rad, float* __restrict__ out) {
    __shared__ float red[256];
    const int t = threadIdx.x;
    float acc = 0.0f;
    for (int i = t; i < 16 * RADIUS; i += 256) {
        int bb = i >> 9;
        int rr = i & (RADIUS - 1);
        float o = rad[(size_t)bb * RADIUS + rr];
        float gg = rad[(size_t)(bb + 16) * RADIUS + rr];
        acc += fabsf(o - gg);
    }
    red[t] = acc;
    __syncthreads();
    for (int off = 128; off > 0; off >>= 1) {
        if (t < off) red[t] += red[t + off];
        __syncthreads();
    }
    if (t == 0) {
        out[0] = red[0] / ((float)S * (float)S) / (16.0f * (float)RADIUS);
    }
}

extern "C" void kernel_launch(void* const* d_in, const int* in_sizes, int n_in,
                              void* d_out, int out_size, void* d_ws, size_t ws_size,
                              hipStream_t stream) {
    const float* outp = (const float*)d_in[0];
    const float* tgtp = (const float*)d_in[1];
    float* dout = (float*)d_out;

    char* ws = (char*)d_ws;
    float* rad = (float*)ws;                                       // 64 KB
    const size_t partBytes = (size_t)NIMG * PBX * 512 * sizeof(float);  // 8.45 MB
    float* partial = (float*)(ws + 65536);
    float2* WpT = (float2*)(ws + 65536 + partBytes);
    const size_t perImg = (size_t)512 * 1024 * sizeof(float2);     // 4 MB / image
    size_t used = 65536 + partBytes;
    size_t avail = (ws_size > used) ? (ws_size - used) : 0;
    int chunk = (int)(avail / perImg);
    if (chunk > NIMG) chunk = NIMG;
    if (chunk < 1) chunk = 1;

    for (int base = 0; base < NIMG; base += chunk) {
        int c = (NIMG - base < chunk) ? (NIMG - base) : chunk;
        fft_rows<<<dim3(128, c), 256, 0, stream>>>(outp, tgtp, WpT, base);
        fft_cols_bin2<<<dim3(PBX, c), 512, 0, stream>>>(WpT, partial, base);
    }

    reduce_partials<<<NIMG, 512, 0, stream>>>(partial, rad);
    final_loss<<<1, 256, 0, stream>>>(rad, dout);
}

// Round 15
// 180.813 us; speedup vs baseline: 1.0370x; 1.0370x over previous
//
#include <hip/hip_runtime.h>
#include <math.h>

#define S 1024
#define RADIUS 512
#define NIMG 32   // 16 "output" images then 16 "target" images
#define PBX 129   // pass-B blocks per image (u-groups of 4)

// ---------------------------------------------------------------------------
// Complex helpers
// ---------------------------------------------------------------------------
__device__ __forceinline__ float2 cmul(float2 a, float2 b) {
    return make_float2(a.x * b.x - a.y * b.y, a.x * b.y + a.y * b.x);
}
__device__ __forceinline__ float2 cadd(float2 a, float2 b) { return make_float2(a.x + b.x, a.y + b.y); }
__device__ __forceinline__ float2 csub(float2 a, float2 b) { return make_float2(a.x - b.x, a.y - b.y); }

// W_16^k, k=0..7
__device__ const float2 C16[8] = {
    {1.0f, 0.0f},
    {0.92387953251128674f, -0.38268343236508978f},
    {0.70710678118654757f, -0.70710678118654746f},
    {0.38268343236508984f, -0.92387953251128674f},
    {0.0f, -1.0f},
    {-0.38268343236508973f, -0.92387953251128674f},
    {-0.70710678118654746f, -0.70710678118654757f},
    {-0.92387953251128663f, -0.38268343236508989f},
};
// W_8^k, k=0..3
__device__ const float2 C8T[4] = {
    {1.0f, 0.0f},
    {0.70710678118654757f, -0.70710678118654746f},
    {0.0f, -1.0f},
    {-0.70710678118654746f, -0.70710678118654757f},
};
// W512^m, m=0..7
__device__ const float2 W512T[8] = {
    {1.0f, 0.0f},
    {0.99992470183914454f, -0.012271538285719925f},
    {0.99969881869620425f, -0.024541228522912288f},
    {0.99932238458834954f, -0.036807222941358832f},
    {0.99879545620517241f, -0.049067674327418015f},
    {0.99811811290014918f, -0.061320736302208578f},
    {0.99729045667869021f, -0.073564563599667426f},
    {0.99631261218277800f, -0.085797312344439894f},
};
// W64^k, k=0..7
__device__ const float2 W64T[8] = {
    {1.0f, 0.0f},
    {0.99518472667219693f, -0.098017140329560604f},
    {0.98078528040323044f, -0.19509032201612825f},
    {0.95694033573220886f, -0.29028467725446233f},
    {0.92387953251128674f, -0.38268343236508978f},
    {0.88192126434835505f, -0.47139673682599764f},
    {0.83146961230254524f, -0.55557023301960218f},
    {0.77301045336273699f, -0.63439328416364549f},
};
// W128^h (plain order), h=0..7
__device__ const float2 W128P[8] = {
    {1.0f, 0.0f},
    {0.99879545620517241f, -0.049067674327418015f},
    {0.99518472667219693f, -0.098017140329560604f},
    {0.98917650996478101f, -0.14673047445536175f},
    {0.98078528040323044f, -0.19509032201612825f},
    {0.97003125319454397f, -0.24298017990326390f},
    {0.95694033573220886f, -0.29028467725446233f},
    {0.94154406518302081f, -0.33688985339222005f},
};
// W1024^l (plain order), l=0..7
__device__ const float2 W1024P[8] = {
    {1.0f, 0.0f},
    {0.99998117528260111f, -0.0061358846491544753f},
    {0.99992470183914454f, -0.012271538285719925f},
    {0.99983058179582340f, -0.018406729905804820f},
    {0.99969881869620425f, -0.024541228522912288f},
    {0.99952941750109314f, -0.030674803176636626f},
    {0.99932238458834954f, -0.036807222941358832f},
    {0.99907772775264536f, -0.042938256934940820f},
};

// 4 radix-2 DIF stages over 16 register elements (pass A)
__device__ __forceinline__ void fft16(float2 r[16], float2 T) {
    float2 tc[8];
    #pragma unroll
    for (int u = 0; u < 8; ++u) tc[u] = cmul(T, C16[u]);
    #pragma unroll
    for (int u = 0; u < 8; ++u) {
        float2 a = r[u], b = r[u + 8];
        r[u] = cadd(a, b);
        r[u + 8] = cmul(csub(a, b), tc[u]);
    }
    T = cmul(T, T);
    #pragma unroll
    for (int u = 0; u < 4; ++u) tc[u] = cmul(T, C16[2 * u]);
    #pragma unroll
    for (int g = 0; g < 2; ++g)
        #pragma unroll
        for (int u = 0; u < 4; ++u) {
            int lo = g * 8 + u;
            float2 a = r[lo], b = r[lo + 4];
            r[lo] = cadd(a, b);
            r[lo + 4] = cmul(csub(a, b), tc[u]);
        }
    T = cmul(T, T);
    #pragma unroll
    for (int u = 0; u < 2; ++u) tc[u] = cmul(T, C16[4 * u]);
    #pragma unroll
    for (int g = 0; g < 4; ++g)
        #pragma unroll
        for (int u = 0; u < 2; ++u) {
            int lo = g * 4 + u;
            float2 a = r[lo], b = r[lo + 2];
            r[lo] = cadd(a, b);
            r[lo + 2] = cmul(csub(a, b), tc[u]);
        }
    T = cmul(T, T);
    #pragma unroll
    for (int g = 0; g < 8; ++g) {
        int lo = g * 2;
        float2 a = r[lo], b = r[lo + 1];
        r[lo] = cadd(a, b);
        r[lo + 1] = cmul(csub(a, b), T);
    }
}

// 3 radix-2 DIF stages over 8 register elements
__device__ __forceinline__ void fft8(float2 r[8], float2 T) {
    float2 tc[4];
    #pragma unroll
    for (int u = 0; u < 4; ++u) tc[u] = cmul(T, C8T[u]);
    #pragma unroll
    for (int u = 0; u < 4; ++u) {
        float2 a = r[u], b = r[u + 4];
        r[u] = cadd(a, b);
        r[u + 4] = cmul(csub(a, b), tc[u]);
    }
    T = cmul(T, T);
    #pragma unroll
    for (int u = 0; u < 2; ++u) tc[u] = cmul(T, C8T[2 * u]);
    #pragma unroll
    for (int g = 0; g < 2; ++g)
        #pragma unroll
        for (int u = 0; u < 2; ++u) {
            int lo = g * 4 + u;
            float2 a = r[lo], b = r[lo + 2];
            r[lo] = cadd(a, b);
            r[lo + 2] = cmul(csub(a, b), tc[u]);
        }
    T = cmul(T, T);
    #pragma unroll
    for (int g = 0; g < 4; ++g) {
        int lo = g * 2;
        float2 a = r[lo], b = r[lo + 1];
        r[lo] = cadd(a, b);
        r[lo + 1] = cmul(csub(a, b), T);
    }
}

// Last 2 DIF stages (1024-pt, pass A): quad-perm shuffles across c = tau&3
__device__ __forceinline__ void fft_last2(float2 r[16], int c) {
    #pragma unroll
    for (int m = 0; m < 16; ++m) {
        float vx = __shfl_xor(r[m].x, 2, 64);
        float vy = __shfl_xor(r[m].y, 2, 64);
        if (c & 2) {
            float dx = vx - r[m].x, dy = vy - r[m].y;
            if (c & 1) { r[m].x = dy; r[m].y = -dx; }
            else       { r[m].x = dx; r[m].y = dy; }
        } else {
            r[m].x += vx; r[m].y += vy;
        }
    }
    #pragma unroll
    for (int m = 0; m < 16; ++m) {
        float vx = __shfl_xor(r[m].x, 1, 64);
        float vy = __shfl_xor(r[m].y, 1, 64);
        if (c & 1) { r[m].x = vx - r[m].x; r[m].y = vy - r[m].y; }
        else       { r[m].x += vx; r[m].y += vy; }
    }
}

__device__ __forceinline__ int bitrev3(int x) {
    return ((x & 1) << 2) | (x & 2) | ((x >> 2) & 1);
}

// ---------------------------------------------------------------------------
// Pass A (ROUND 14): DE-LOCKSTEP. Same validated math as R13, but 256-thread /
// 4-wave blocks (grid 128 x c), 16 KB LDS. Rationale: R11-R13 showed fft_rows
// pinned at ~90 us with VALU/DS/VMEM each ~30% and dur invariant to L3-vs-HBM
// input -> pipes behave sum-like (phase lockstep of 8-wave barrier blocks).
// 8 independent 4-wave blocks/CU give the CU phase-offset work so pipes can
// overlap across blocks. Staging tile [512][4] -> 32 B/uu stores (two blocks
// share a 64 B line; L2 merges). Falsifier: WRITE_SIZE inflation.
// ---------------------------------------------------------------------------
__global__ __launch_bounds__(256, 4)
void fft_rows(const float* __restrict__ outp, const float* __restrict__ tgtp,
              float2* __restrict__ WpT, int imgBase) {
    __shared__ float2 buf[2048];   // 16 KB: 4 x 512-slot wave regions / staging
    const int t = threadIdx.x;
    const int w = t >> 6, tau = t & 63;
    const int yy = blockIdx.x * 4 + w;
    const int i = blockIdx.y, g = imgBase + i;
    const float* img = (g < 16 ? outp : tgtp) + (size_t)(g & 15) * S * S;
    const float* r0 = img + (size_t)(2 * yy) * S;
    const float* r1 = r0 + S;

    float2* wb = buf + (w << 9);
    float* wf = (float*)wb;        // 1024 floats, wave-private

    float2 r[16];
    // row0: float4 loads -> LDS bounce -> r[].x  (same-wave DS ordering)
    #pragma unroll
    for (int q = 0; q < 4; ++q) {
        float4 v = *reinterpret_cast<const float4*>(&r0[q * 256 + 4 * tau]);
        *reinterpret_cast<float4*>(&wf[q * 256 + 4 * tau]) = v;
    }
    #pragma unroll
    for (int j = 0; j < 16; ++j) r[j].x = wf[64 * j + tau];
    // row1
    #pragma unroll
    for (int q = 0; q < 4; ++q) {
        float4 v = *reinterpret_cast<const float4*>(&r1[q * 256 + 4 * tau]);
        *reinterpret_cast<float4*>(&wf[q * 256 + 4 * tau]) = v;
    }
    #pragma unroll
    for (int j = 0; j < 16; ++j) r[j].y = wf[64 * j + tau];

    // T = W1024^tau (table product)
    fft16(r, cmul(W128P[tau >> 3], W1024P[tau & 7]));

    // ---- two-phase mid-transpose, wave-private 512-slot region (R12) ----
    const int b = tau >> 2, c = tau & 3;
    float2 ex[8];
    #pragma unroll
    for (int j = 0; j < 8; ++j) wb[(j << 6) | (tau ^ (j << 2))] = r[j];
    if (b < 8) {
        #pragma unroll
        for (int m = 0; m < 8; ++m)  r[m]      = wb[((b & 7) << 6) + 4 * ((m ^ b) & 15) + c];
        #pragma unroll
        for (int m = 8; m < 16; ++m) ex[m - 8] = wb[((b & 7) << 6) + 4 * ((m ^ b) & 15) + c];
    }
    #pragma unroll
    for (int j = 8; j < 16; ++j) wb[((j & 7) << 6) | (tau ^ (j << 2))] = r[j];
    if (b >= 8) {
        #pragma unroll
        for (int m = 0; m < 8; ++m)  r[m]      = wb[((b & 7) << 6) + 4 * ((m ^ b) & 15) + c];
        #pragma unroll
        for (int m = 8; m < 16; ++m) ex[m - 8] = wb[((b & 7) << 6) + 4 * ((m ^ b) & 15) + c];
    }
    #pragma unroll
    for (int m = 8; m < 16; ++m) r[m] = ex[m - 8];

    fft16(r, W64T[c]);          // T = W64^c
    fft_last2(r, c);

    // ---- two-phase output staging + float4 coalesced store ----
    const int yy0 = blockIdx.x * 4;
    float2* dst = WpT + (size_t)i * 512 * 1024;
    #pragma unroll
    for (int h = 0; h < 2; ++h) {
        if ((c & 1) == h) {                      // this half's 32 lanes own k-half h
            #pragma unroll
            for (int m = 0; m < 16; ++m) {
                int n = (b << 6) + 4 * m + c;
                int kh = (int)(__brev((unsigned)n) >> 22) & 511;
                buf[(w << 9) | (kh ^ (w << 1))] = r[m];   // own wave region
            }
        }
        __syncthreads();
        #pragma unroll
        for (int q = 0; q < 4; ++q) {
            int idx4 = q * 256 + t;              // 0..1023 = 512 uu x 2 pairs
            int p2 = (idx4 & 1) << 1;            // wv pair base: 0,2
            int uu = idx4 >> 1;                  // 0..511
            float2 v0 = buf[((p2 + 0) << 9) | (uu ^ ((p2 + 0) << 1))];
            float2 v1 = buf[((p2 + 1) << 9) | (uu ^ ((p2 + 1) << 1))];
            float4 vv = make_float4(v0.x, v0.y, v1.x, v1.y);
            *reinterpret_cast<float4*>(&dst[(size_t)(uu + (h << 9)) * 512 + yy0 + p2]) = vv;
        }
        __syncthreads();
    }
}

// ---------------------------------------------------------------------------
// Pass B (unchanged — validated R13): split-wave FFT + combine + PER-WAVE
// scan binning (5 barriers, zero atomics).
// ---------------------------------------------------------------------------
__global__ __launch_bounds__(512, 4)
void fft_cols_bin2(const float2* __restrict__ WpT, float* __restrict__ partial, int imgBase) {
    __shared__ float2 tbuf[8 * 512];      // 32 KB, multi-phase aliased
    const int t = threadIdx.x;
    const int w = t >> 6, tau = t & 63;
    const int i = blockIdx.y, g = imgBase + i;
    const int l = w >> 1;                 // local u index 0..3
    const int u = blockIdx.x * 4 + l;     // 0..515
    const int setb = w & 1;               // 0: X0 FFT (v=f), 1: X1 FFT (v=f+512)
    const bool active = (u <= 512);

    const int b3 = tau >> 3, lam = tau & 7;
    float2 X[8];
    float2* mb = tbuf + (w << 9);

    if (active) {
        const float2* Wimg = WpT + (size_t)i * 512 * 1024;
        const int mu = (1024 - u) & 1023;
        const float2* rowA = Wimg + (size_t)u * 512;
        const float2* rowM = Wimg + (size_t)mu * 512;

        #pragma unroll
        for (int j = 0; j < 8; ++j) {
            float2 A = rowA[64 * j + tau];
            float2 M = rowM[64 * j + tau];
            X[j] = (setb == 0)
                 ? make_float2(0.5f * (A.x + M.x), 0.5f * (A.y - M.y))
                 : make_float2(0.5f * (A.y + M.y), 0.5f * (M.x - A.x));
        }

        // Phase 1; T = W512^tau = W64^{b3} * W512^{lam}
        fft8(X, cmul(W64T[b3], W512T[lam]));

        // Transpose 1 (wave-private, swizzled, conflict-free)
        #pragma unroll
        for (int j = 0; j < 8; ++j) mb[(j << 6) | (tau ^ (j << 3) ^ j)] = X[j];
        #pragma unroll
        for (int c = 0; c < 8; ++c) X[c] = mb[(b3 << 6) | (((c ^ b3) << 3) | (lam ^ b3))];

        // Phase 2; T = W64^{lam}
        fft8(X, W64T[lam]);

        // Transpose 2
        #pragma unroll
        for (int c = 0; c < 8; ++c) mb[(b3 << 6) | (((c ^ b3) << 3) | (lam ^ b3))] = X[c];
        #pragma unroll
        for (int d = 0; d < 8; ++d) X[d] = mb[(b3 << 6) | (((lam ^ b3) << 3) | (d ^ b3))];

        // Phase 3 (T = 1)
        fft8(X, make_float2(1.0f, 0.0f));

        // Publish in NATURAL-f order: X[d] is freq f = 64*rev3(d)+8*rev3(lam)+rev3(b3)
        const int base9 = 8 * bitrev3(lam) + bitrev3(b3);
        #pragma unroll
        for (int d = 0; d < 8; ++d) {
            mb[(bitrev3(d) << 6) + base9] = X[d];
        }
    }
    __syncthreads();   // (1) cross-wave spectra exchange

    float p[8];
    if (active) {
        const float2* b0 = tbuf + ((w & ~1) << 9);   // X0-hat, natural-f
        const float2* b1 = tbuf + ((w | 1) << 9);    // X1-hat, natural-f
        const float2 Wtau = cmul(W128P[tau >> 3], W1024P[tau & 7]);  // W1024^tau
        #pragma unroll
        for (int m = 0; m < 8; ++m) {
            const int f = tau + 64 * m;
            float2 x0 = b0[f];
            float2 x1 = b1[f];
            float2 Wf = cmul(Wtau, C16[m]);          // W1024^f
            float2 wx = cmul(Wf, x1);
            float2 G = (setb == 0) ? cadd(x0, wx)    // v = f
                                   : csub(x0, wx);   // v = f + 512
            p[m] = G.x * G.x + G.y * G.y;
        }
    }
    __syncthreads();   // (2) spectra reads done -> safe to alias Prow

    float* Prow = (float*)tbuf;                      // floats [0..4095] = [4][1024]
    float* wpref = ((float*)tbuf) + 4096;            // floats [4096..8191] = [8][512]
    if (active) {
        #pragma unroll
        for (int m = 0; m < 8; ++m) {
            const int v = tau + 64 * m + (setb << 9);
            Prow[(l << 10) + v] = p[m];
        }
    }
    __syncthreads();   // (3) Prow ready

    // ---- per-wave scan + ring windows: wave w owns row (l = w>>1, mir = w&1) ----
    const int mir = w & 1;
    const int uu = blockIdx.x * 4 + l;
    const bool valid = (uu <= 512) && (!mir || (uu >= 1 && uu <= 511));
    const float* PR = Prow + (l << 10);
    float* myp = wpref + (w << 9);

    float carry = 0.0f;
    #pragma unroll
    for (int k = 0; k < 8; ++k) {
        const int idx = (k << 6) + tau;
        float F = 0.0f;
        if (valid) {
            F = mir ? (PR[idx + 1] + PR[(1024 - idx) & 1023])   // mirror row
                    : (PR[idx] + PR[1023 - idx]);               // direct fold
        }
        float s = F;
        #pragma unroll
        for (int off = 1; off < 64; off <<= 1) {
            float n = __shfl_up(s, off, 64);
            if (tau >= off) s += n;
        }
        myp[idx] = s + carry;                 // inclusive prefix over 512
        carry += __shfl(s, 63, 64);           // chunk total
    }
    // window lookups: thread tau resolves rings r = tau + 64m from OWN prefix
    const float cuv = mir ? ((float)uu - 0.5f)
                          : ((uu < 512) ? ((float)uu + 0.5f) : 511.5f);
    const float cu2 = cuv * cuv;              // exact in f32
    float acc[8];
    #pragma unroll
    for (int m = 0; m < 8; ++m) {
        acc[m] = 0.0f;
        if (valid) {
            const int r = tau + (m << 6);
            const float r2  = (float)(r * r);
            const float r12 = (float)((r + 1) * (r + 1));
            const float Bv = r12 - cu2;       // exact
            if (Bv > 0.0f) {
                const float Av = r2 - cu2;    // exact
                float cvlo = (Av > 0.0f) ? sqrtf(Av) : 0.0f;
                float cvhi = sqrtf(Bv);
                int vlo = (int)ceilf(cvlo - 0.5f);
                int vhi = (int)ceilf(cvhi - 0.5f);
                if (vhi > 512) vhi = 512;
                if (vlo < 0) vlo = 0;
                if (vhi > vlo) {
                    float hi = myp[vhi - 1];
                    float lo = (vlo > 0) ? myp[vlo - 1] : 0.0f;
                    acc[m] = hi - lo;
                }
            }
        }
    }
    __syncthreads();   // (4) all waves done with Prow/wpref reads

    float* wavebins = (float*)tbuf;           // floats [0..4095] = [8][512]
    #pragma unroll
    for (int m = 0; m < 8; ++m) {
        wavebins[(w << 9) + (m << 6) + tau] = acc[m];
    }
    __syncthreads();   // (5) wavebins ready

    float sum = 0.0f;
    #pragma unroll
    for (int ww = 0; ww < 8; ++ww) sum += wavebins[(ww << 9) + t];
    // per-block partial; every slot written every call (re-poison safe)
    partial[(((size_t)g * PBX) + blockIdx.x) * 512 + t] = sum;
}

// ---------------------------------------------------------------------------
// Fold partials -> rad  (block per image, 129 block-partials)
// ---------------------------------------------------------------------------
__global__ __launch_bounds__(512)
void reduce_partials(const float* __restrict__ partial, float* __restrict__ rad) {
    const int g = blockIdx.x;
    const int t = threadIdx.x;
    const float* p = partial + (size_t)g * PBX * 512;
    float s = 0.0f;
    for (int b = 0; b < PBX; ++b) s += p[(size_t)b * 512 + t];
    rad[(size_t)g * 512 + t] = s;
}

// ---------------------------------------------------------------------------
// Final: loss = mean(|rad_out - rad_tgt|) / S^2
// ---------------------------------------------------------------------------
__global__ __launch_bounds__(256)
void final_loss(const float* __restrict__ rad, float* __restrict__ out) {
    __shared__ float red[256];
    const int t = threadIdx.x;
    float acc = 0.0f;
    for (int i = t; i < 16 * RADIUS; i += 256) {
        int bb = i >> 9;
        int rr = i & (RADIUS - 1);
        float o = rad[(size_t)bb * RADIUS + rr];
        float gg = rad[(size_t)(bb + 16) * RADIUS + rr];
        acc += fabsf(o - gg);
    }
    red[t] = acc;
    __syncthreads();
    for (int off = 128; off > 0; off >>= 1) {
        if (t < off) red[t] += red[t + off];
        __syncthreads();
    }
    if (t == 0) {
        out[0] = red[0] / ((float)S * (float)S) / (16.0f * (float)RADIUS);
    }
}

extern "C" void kernel_launch(void* const* d_in, const int* in_sizes, int n_in,
                              void* d_out, int out_size, void* d_ws, size_t ws_size,
                              hipStream_t stream) {
    const float* outp = (const float*)d_in[0];
    const float* tgtp = (const float*)d_in[1];
    float* dout = (float*)d_out;

    char* ws = (char*)d_ws;
    float* rad = (float*)ws;                                       // 64 KB
    const size_t partBytes = (size_t)NIMG * PBX * 512 * sizeof(float);  // 8.45 MB
    float* partial = (float*)(ws + 65536);
    float2* WpT = (float2*)(ws + 65536 + partBytes);
    const size_t perImg = (size_t)512 * 1024 * sizeof(float2);     // 4 MB / image
    size_t used = 65536 + partBytes;
    size_t avail = (ws_size > used) ? (ws_size - used) : 0;
    int chunk = (int)(avail / perImg);
    if (chunk > NIMG) chunk = NIMG;
    if (chunk < 1) chunk = 1;

    for (int base = 0; base < NIMG; base += chunk) {
        int c = (NIMG - base < chunk) ? (NIMG - base) : chunk;
        fft_rows<<<dim3(128, c), 256, 0, stream>>>(outp, tgtp, WpT, base);
        fft_cols_bin2<<<dim3(PBX, c), 512, 0, stream>>>(WpT, partial, base);
    }

    reduce_partials<<<NIMG, 512, 0, stream>>>(partial, rad);
    final_loss<<<1, 256, 0, stream>>>(rad, dout);
}

// Round 16
// 162.637 us; speedup vs baseline: 1.1529x; 1.1118x over previous
//
#include <hip/hip_runtime.h>
#include <math.h>

#define S 1024
#define RADIUS 512
#define NIMG 32   // 16 "output" images then 16 "target" images
#define PBX 129   // pass-B blocks per image (u-groups of 4)

// ---------------------------------------------------------------------------
// Complex helpers
// ---------------------------------------------------------------------------
__device__ __forceinline__ float2 cmul(float2 a, float2 b) {
    return make_float2(a.x * b.x - a.y * b.y, a.x * b.y + a.y * b.x);
}
__device__ __forceinline__ float2 cadd(float2 a, float2 b) { return make_float2(a.x + b.x, a.y + b.y); }
__device__ __forceinline__ float2 csub(float2 a, float2 b) { return make_float2(a.x - b.x, a.y - b.y); }

// W_16^k, k=0..7
__device__ const float2 C16[8] = {
    {1.0f, 0.0f},
    {0.92387953251128674f, -0.38268343236508978f},
    {0.70710678118654757f, -0.70710678118654746f},
    {0.38268343236508984f, -0.92387953251128674f},
    {0.0f, -1.0f},
    {-0.38268343236508973f, -0.92387953251128674f},
    {-0.70710678118654746f, -0.70710678118654757f},
    {-0.92387953251128663f, -0.38268343236508989f},
};
// W_8^k, k=0..3
__device__ const float2 C8T[4] = {
    {1.0f, 0.0f},
    {0.70710678118654757f, -0.70710678118654746f},
    {0.0f, -1.0f},
    {-0.70710678118654746f, -0.70710678118654757f},
};
// W512^m, m=0..7
__device__ const float2 W512T[8] = {
    {1.0f, 0.0f},
    {0.99992470183914454f, -0.012271538285719925f},
    {0.99969881869620425f, -0.024541228522912288f},
    {0.99932238458834954f, -0.036807222941358832f},
    {0.99879545620517241f, -0.049067674327418015f},
    {0.99811811290014918f, -0.061320736302208578f},
    {0.99729045667869021f, -0.073564563599667426f},
    {0.99631261218277800f, -0.085797312344439894f},
};
// W64^k, k=0..7
__device__ const float2 W64T[8] = {
    {1.0f, 0.0f},
    {0.99518472667219693f, -0.098017140329560604f},
    {0.98078528040323044f, -0.19509032201612825f},
    {0.95694033573220886f, -0.29028467725446233f},
    {0.92387953251128674f, -0.38268343236508978f},
    {0.88192126434835505f, -0.47139673682599764f},
    {0.83146961230254524f, -0.55557023301960218f},
    {0.77301045336273699f, -0.63439328416364549f},
};
// W128^h (plain order), h=0..7
__device__ const float2 W128P[8] = {
    {1.0f, 0.0f},
    {0.99879545620517241f, -0.049067674327418015f},
    {0.99518472667219693f, -0.098017140329560604f},
    {0.98917650996478101f, -0.14673047445536175f},
    {0.98078528040323044f, -0.19509032201612825f},
    {0.97003125319454397f, -0.24298017990326390f},
    {0.95694033573220886f, -0.29028467725446233f},
    {0.94154406518302081f, -0.33688985339222005f},
};
// W1024^l (plain order), l=0..7
__device__ const float2 W1024P[8] = {
    {1.0f, 0.0f},
    {0.99998117528260111f, -0.0061358846491544753f},
    {0.99992470183914454f, -0.012271538285719925f},
    {0.99983058179582340f, -0.018406729905804820f},
    {0.99969881869620425f, -0.024541228522912288f},
    {0.99952941750109314f, -0.030674803176636626f},
    {0.99932238458834954f, -0.036807222941358832f},
    {0.99907772775264536f, -0.042938256934940820f},
};

// 4 radix-2 DIF stages over 16 register elements (pass A)
__device__ __forceinline__ void fft16(float2 r[16], float2 T) {
    float2 tc[8];
    #pragma unroll
    for (int u = 0; u < 8; ++u) tc[u] = cmul(T, C16[u]);
    #pragma unroll
    for (int u = 0; u < 8; ++u) {
        float2 a = r[u], b = r[u + 8];
        r[u] = cadd(a, b);
        r[u + 8] = cmul(csub(a, b), tc[u]);
    }
    T = cmul(T, T);
    #pragma unroll
    for (int u = 0; u < 4; ++u) tc[u] = cmul(T, C16[2 * u]);
    #pragma unroll
    for (int g = 0; g < 2; ++g)
        #pragma unroll
        for (int u = 0; u < 4; ++u) {
            int lo = g * 8 + u;
            float2 a = r[lo], b = r[lo + 4];
            r[lo] = cadd(a, b);
            r[lo + 4] = cmul(csub(a, b), tc[u]);
        }
    T = cmul(T, T);
    #pragma unroll
    for (int u = 0; u < 2; ++u) tc[u] = cmul(T, C16[4 * u]);
    #pragma unroll
    for (int g = 0; g < 4; ++g)
        #pragma unroll
        for (int u = 0; u < 2; ++u) {
            int lo = g * 4 + u;
            float2 a = r[lo], b = r[lo + 2];
            r[lo] = cadd(a, b);
            r[lo + 2] = cmul(csub(a, b), tc[u]);
        }
    T = cmul(T, T);
    #pragma unroll
    for (int g = 0; g < 8; ++g) {
        int lo = g * 2;
        float2 a = r[lo], b = r[lo + 1];
        r[lo] = cadd(a, b);
        r[lo + 1] = cmul(csub(a, b), T);
    }
}

// 3 radix-2 DIF stages over 8 register elements
__device__ __forceinline__ void fft8(float2 r[8], float2 T) {
    float2 tc[4];
    #pragma unroll
    for (int u = 0; u < 4; ++u) tc[u] = cmul(T, C8T[u]);
    #pragma unroll
    for (int u = 0; u < 4; ++u) {
        float2 a = r[u], b = r[u + 4];
        r[u] = cadd(a, b);
        r[u + 4] = cmul(csub(a, b), tc[u]);
    }
    T = cmul(T, T);
    #pragma unroll
    for (int u = 0; u < 2; ++u) tc[u] = cmul(T, C8T[2 * u]);
    #pragma unroll
    for (int g = 0; g < 2; ++g)
        #pragma unroll
        for (int u = 0; u < 2; ++u) {
            int lo = g * 4 + u;
            float2 a = r[lo], b = r[lo + 2];
            r[lo] = cadd(a, b);
            r[lo + 2] = cmul(csub(a, b), tc[u]);
        }
    T = cmul(T, T);
    #pragma unroll
    for (int g = 0; g < 4; ++g) {
        int lo = g * 2;
        float2 a = r[lo], b = r[lo + 1];
        r[lo] = cadd(a, b);
        r[lo + 1] = cmul(csub(a, b), T);
    }
}

// Last 2 DIF stages (1024-pt, pass A): quad-perm shuffles across c = tau&3
__device__ __forceinline__ void fft_last2(float2 r[16], int c) {
    #pragma unroll
    for (int m = 0; m < 16; ++m) {
        float vx = __shfl_xor(r[m].x, 2, 64);
        float vy = __shfl_xor(r[m].y, 2, 64);
        if (c & 2) {
            float dx = vx - r[m].x, dy = vy - r[m].y;
            if (c & 1) { r[m].x = dy; r[m].y = -dx; }
            else       { r[m].x = dx; r[m].y = dy; }
        } else {
            r[m].x += vx; r[m].y += vy;
        }
    }
    #pragma unroll
    for (int m = 0; m < 16; ++m) {
        float vx = __shfl_xor(r[m].x, 1, 64);
        float vy = __shfl_xor(r[m].y, 1, 64);
        if (c & 1) { r[m].x = vx - r[m].x; r[m].y = vy - r[m].y; }
        else       { r[m].x += vx; r[m].y += vy; }
    }
}

__device__ __forceinline__ int bitrev3(int x) {
    return ((x & 1) << 2) | (x & 2) | ((x >> 2) & 1);
}

// ---------------------------------------------------------------------------
// Pass A (ROUND 16): R13-exact structure (best timed config), with ONE change:
// all 8 global float4 loads (row0 + row1) are issued up front, so the row1
// HBM round-trip overlaps the row0 LDS bounce (compiler waits vmcnt(4) for
// the row0 batch only). R13 exposed two serialized HBM round-trips per wave.
// Peak live VGPRs unchanged (~56): the 8 float4 die before the r[16]+ex[8]
// peak. Falsifier: VGPR>64 / WRITE_SIZE inflation = spill -> revert.
// ---------------------------------------------------------------------------
__global__ __launch_bounds__(512, 4)
void fft_rows(const float* __restrict__ outp, const float* __restrict__ tgtp,
              float2* __restrict__ WpT, int imgBase) {
    __shared__ float2 buf[4096];   // 32 KB: 8 x 512-slot wave regions / staging
    const int t = threadIdx.x;
    const int w = t >> 6, tau = t & 63;
    const int yy = blockIdx.x * 8 + w;
    const int i = blockIdx.y, g = imgBase + i;
    const float* img = (g < 16 ? outp : tgtp) + (size_t)(g & 15) * S * S;
    const float* r0 = img + (size_t)(2 * yy) * S;
    const float* r1 = r0 + S;

    float2* wb = buf + (w << 9);
    float* wf = (float*)wb;        // 1024 floats, wave-private

    // issue ALL 8 loads up front: row1's latency hides under row0's bounce
    float4 va[4], vb[4];
    #pragma unroll
    for (int q = 0; q < 4; ++q) va[q] = *reinterpret_cast<const float4*>(&r0[q * 256 + 4 * tau]);
    #pragma unroll
    for (int q = 0; q < 4; ++q) vb[q] = *reinterpret_cast<const float4*>(&r1[q * 256 + 4 * tau]);

    float2 r[16];
    // row0 bounce -> r[].x  (same-wave DS program order, no barrier)
    #pragma unroll
    for (int q = 0; q < 4; ++q) *reinterpret_cast<float4*>(&wf[q * 256 + 4 * tau]) = va[q];
    #pragma unroll
    for (int j = 0; j < 16; ++j) r[j].x = wf[64 * j + tau];
    // row1 bounce -> r[].y  (writes follow reads in program order: safe)
    #pragma unroll
    for (int q = 0; q < 4; ++q) *reinterpret_cast<float4*>(&wf[q * 256 + 4 * tau]) = vb[q];
    #pragma unroll
    for (int j = 0; j < 16; ++j) r[j].y = wf[64 * j + tau];

    // T = W1024^tau (table product)
    fft16(r, cmul(W128P[tau >> 3], W1024P[tau & 7]));

    // ---- two-phase mid-transpose, wave-private 512-slot region (R12) ----
    const int b = tau >> 2, c = tau & 3;
    float2 ex[8];
    #pragma unroll
    for (int j = 0; j < 8; ++j) wb[(j << 6) | (tau ^ (j << 2))] = r[j];
    if (b < 8) {
        #pragma unroll
        for (int m = 0; m < 8; ++m)  r[m]      = wb[((b & 7) << 6) + 4 * ((m ^ b) & 15) + c];
        #pragma unroll
        for (int m = 8; m < 16; ++m) ex[m - 8] = wb[((b & 7) << 6) + 4 * ((m ^ b) & 15) + c];
    }
    #pragma unroll
    for (int j = 8; j < 16; ++j) wb[((j & 7) << 6) | (tau ^ (j << 2))] = r[j];
    if (b >= 8) {
        #pragma unroll
        for (int m = 0; m < 8; ++m)  r[m]      = wb[((b & 7) << 6) + 4 * ((m ^ b) & 15) + c];
        #pragma unroll
        for (int m = 8; m < 16; ++m) ex[m - 8] = wb[((b & 7) << 6) + 4 * ((m ^ b) & 15) + c];
    }
    #pragma unroll
    for (int m = 8; m < 16; ++m) r[m] = ex[m - 8];

    fft16(r, W64T[c]);          // T = W64^c
    fft_last2(r, c);

    // ---- two-phase output staging + float4 coalesced store ----
    const int yy0 = blockIdx.x * 8;
    float2* dst = WpT + (size_t)i * 512 * 1024;
    #pragma unroll
    for (int h = 0; h < 2; ++h) {
        if ((c & 1) == h) {                      // this half's 32 lanes own k-half h
            #pragma unroll
            for (int m = 0; m < 16; ++m) {
                int n = (b << 6) + 4 * m + c;
                int kh = (int)(__brev((unsigned)n) >> 22) & 511;
                buf[(w << 9) | (kh ^ (w << 1))] = r[m];   // own wave region
            }
        }
        __syncthreads();
        #pragma unroll
        for (int q = 0; q < 4; ++q) {
            int idx4 = q * 512 + t;              // 0..2047 = 512 uu x 4 pairs
            int p2 = (idx4 & 3) << 1;            // wv pair base: 0,2,4,6
            int uu = idx4 >> 2;                  // 0..511
            float2 v0 = buf[((p2 + 0) << 9) | (uu ^ ((p2 + 0) << 1))];
            float2 v1 = buf[((p2 + 1) << 9) | (uu ^ ((p2 + 1) << 1))];
            float4 vv = make_float4(v0.x, v0.y, v1.x, v1.y);
            *reinterpret_cast<float4*>(&dst[(size_t)(uu + (h << 9)) * 512 + yy0 + p2]) = vv;
        }
        __syncthreads();
    }
}

// ---------------------------------------------------------------------------
// Pass B (unchanged — validated R13): split-wave FFT + combine + PER-WAVE
// scan binning (5 barriers, zero atomics).
// ---------------------------------------------------------------------------
__global__ __launch_bounds__(512, 4)
void fft_cols_bin2(const float2* __restrict__ WpT, float* __restrict__ partial, int imgBase) {
    __shared__ float2 tbuf[8 * 512];      // 32 KB, multi-phase aliased
    const int t = threadIdx.x;
    const int w = t >> 6, tau = t & 63;
    const int i = blockIdx.y, g = imgBase + i;
    const int l = w >> 1;                 // local u index 0..3
    const int u = blockIdx.x * 4 + l;     // 0..515
    const int setb = w & 1;               // 0: X0 FFT (v=f), 1: X1 FFT (v=f+512)
    const bool active = (u <= 512);

    const int b3 = tau >> 3, lam = tau & 7;
    float2 X[8];
    float2* mb = tbuf + (w << 9);

    if (active) {
        const float2* Wimg = WpT + (size_t)i * 512 * 1024;
        const int mu = (1024 - u) & 1023;
        const float2* rowA = Wimg + (size_t)u * 512;
        const float2* rowM = Wimg + (size_t)mu * 512;

        #pragma unroll
        for (int j = 0; j < 8; ++j) {
            float2 A = rowA[64 * j + tau];
            float2 M = rowM[64 * j + tau];
            X[j] = (setb == 0)
                 ? make_float2(0.5f * (A.x + M.x), 0.5f * (A.y - M.y))
                 : make_float2(0.5f * (A.y + M.y), 0.5f * (M.x - A.x));
        }

        // Phase 1; T = W512^tau = W64^{b3} * W512^{lam}
        fft8(X, cmul(W64T[b3], W512T[lam]));

        // Transpose 1 (wave-private, swizzled, conflict-free)
        #pragma unroll
        for (int j = 0; j < 8; ++j) mb[(j << 6) | (tau ^ (j << 3) ^ j)] = X[j];
        #pragma unroll
        for (int c = 0; c < 8; ++c) X[c] = mb[(b3 << 6) | (((c ^ b3) << 3) | (lam ^ b3))];

        // Phase 2; T = W64^{lam}
        fft8(X, W64T[lam]);

        // Transpose 2
        #pragma unroll
        for (int c = 0; c < 8; ++c) mb[(b3 << 6) | (((c ^ b3) << 3) | (lam ^ b3))] = X[c];
        #pragma unroll
        for (int d = 0; d < 8; ++d) X[d] = mb[(b3 << 6) | (((lam ^ b3) << 3) | (d ^ b3))];

        // Phase 3 (T = 1)
        fft8(X, make_float2(1.0f, 0.0f));

        // Publish in NATURAL-f order: X[d] is freq f = 64*rev3(d)+8*rev3(lam)+rev3(b3)
        const int base9 = 8 * bitrev3(lam) + bitrev3(b3);
        #pragma unroll
        for (int d = 0; d < 8; ++d) {
            mb[(bitrev3(d) << 6) + base9] = X[d];
        }
    }
    __syncthreads();   // (1) cross-wave spectra exchange

    float p[8];
    if (active) {
        const float2* b0 = tbuf + ((w & ~1) << 9);   // X0-hat, natural-f
        const float2* b1 = tbuf + ((w | 1) << 9);    // X1-hat, natural-f
        const float2 Wtau = cmul(W128P[tau >> 3], W1024P[tau & 7]);  // W1024^tau
        #pragma unroll
        for (int m = 0; m < 8; ++m) {
            const int f = tau + 64 * m;
            float2 x0 = b0[f];
            float2 x1 = b1[f];
            float2 Wf = cmul(Wtau, C16[m]);          // W1024^f
            float2 wx = cmul(Wf, x1);
            float2 G = (setb == 0) ? cadd(x0, wx)    // v = f
                                   : csub(x0, wx);   // v = f + 512
            p[m] = G.x * G.x + G.y * G.y;
        }
    }
    __syncthreads();   // (2) spectra reads done -> safe to alias Prow

    float* Prow = (float*)tbuf;                      // floats [0..4095] = [4][1024]
    float* wpref = ((float*)tbuf) + 4096;            // floats [4096..8191] = [8][512]
    if (active) {
        #pragma unroll
        for (int m = 0; m < 8; ++m) {
            const int v = tau + 64 * m + (setb << 9);
            Prow[(l << 10) + v] = p[m];
        }
    }
    __syncthreads();   // (3) Prow ready

    // ---- per-wave scan + ring windows: wave w owns row (l = w>>1, mir = w&1) ----
    const int mir = w & 1;
    const int uu = blockIdx.x * 4 + l;
    const bool valid = (uu <= 512) && (!mir || (uu >= 1 && uu <= 511));
    const float* PR = Prow + (l << 10);
    float* myp = wpref + (w << 9);

    float carry = 0.0f;
    #pragma unroll
    for (int k = 0; k < 8; ++k) {
        const int idx = (k << 6) + tau;
        float F = 0.0f;
        if (valid) {
            F = mir ? (PR[idx + 1] + PR[(1024 - idx) & 1023])   // mirror row
                    : (PR[idx] + PR[1023 - idx]);               // direct fold
        }
        float s = F;
        #pragma unroll
        for (int off = 1; off < 64; off <<= 1) {
            float n = __shfl_up(s, off, 64);
            if (tau >= off) s += n;
        }
        myp[idx] = s + carry;                 // inclusive prefix over 512
        carry += __shfl(s, 63, 64);           // chunk total
    }
    // window lookups: thread tau resolves rings r = tau + 64m from OWN prefix
    const float cuv = mir ? ((float)uu - 0.5f)
                          : ((uu < 512) ? ((float)uu + 0.5f) : 511.5f);
    const float cu2 = cuv * cuv;              // exact in f32
    float acc[8];
    #pragma unroll
    for (int m = 0; m < 8; ++m) {
        acc[m] = 0.0f;
        if (valid) {
            const int r = tau + (m << 6);
            const float r2  = (float)(r * r);
            const float r12 = (float)((r + 1) * (r + 1));
            const float Bv = r12 - cu2;       // exact
            if (Bv > 0.0f) {
                const float Av = r2 - cu2;    // exact
                float cvlo = (Av > 0.0f) ? sqrtf(Av) : 0.0f;
                float cvhi = sqrtf(Bv);
                int vlo = (int)ceilf(cvlo - 0.5f);
                int vhi = (int)ceilf(cvhi - 0.5f);
                if (vhi > 512) vhi = 512;
                if (vlo < 0) vlo = 0;
                if (vhi > vlo) {
                    float hi = myp[vhi - 1];
                    float lo = (vlo > 0) ? myp[vlo - 1] : 0.0f;
                    acc[m] = hi - lo;
                }
            }
        }
    }
    __syncthreads();   // (4) all waves done with Prow/wpref reads

    float* wavebins = (float*)tbuf;           // floats [0..4095] = [8][512]
    #pragma unroll
    for (int m = 0; m < 8; ++m) {
        wavebins[(w << 9) + (m << 6) + tau] = acc[m];
    }
    __syncthreads();   // (5) wavebins ready

    float sum = 0.0f;
    #pragma unroll
    for (int ww = 0; ww < 8; ++ww) sum += wavebins[(ww << 9) + t];
    // per-block partial; every slot written every call (re-poison safe)
    partial[(((size_t)g * PBX) + blockIdx.x) * 512 + t] = sum;
}

// ---------------------------------------------------------------------------
// Fold partials -> rad  (block per image, 129 block-partials)
// ---------------------------------------------------------------------------
__global__ __launch_bounds__(512)
void reduce_partials(const float* __restrict__ partial, float* __restrict__ rad) {
    const int g = blockIdx.x;
    const int t = threadIdx.x;
    const float* p = partial + (size_t)g * PBX * 512;
    float s = 0.0f;
    for (int b = 0; b < PBX; ++b) s += p[(size_t)b * 512 + t];
    rad[(size_t)g * 512 + t] = s;
}

// ---------------------------------------------------------------------------
// Final: loss = mean(|rad_out - rad_tgt|) / S^2
// ---------------------------------------------------------------------------
__global__ __launch_bounds__(256)
void final_loss(const float* __restrict__ rad, float* __restrict__ out) {
    __shared__ float red[256];
    const int t = threadIdx.x;
    float acc = 0.0f;
    for (int i = t; i < 16 * RADIUS; i += 256) {
        int bb = i >> 9;
        int rr = i & (RADIUS - 1);
        float o = rad[(size_t)bb * RADIUS + rr];
        float gg = rad[(size_t)(bb + 16) * RADIUS + rr];
        acc += fabsf(o - gg);
    }
    red[t] = acc;
    __syncthreads();
    for (int off = 128; off > 0; off >>= 1) {
        if (t < off) red[t] += red[t + off];
        __syncthreads();
    }
    if (t == 0) {
        out[0] = red[0] / ((float)S * (float)S) / (16.0f * (float)RADIUS);
    }
}

extern "C" void kernel_launch(void* const* d_in, const int* in_sizes, int n_in,
                              void* d_out, int out_size, void* d_ws, size_t ws_size,
                              hipStream_t stream) {
    const float* outp = (const float*)d_in[0];
    const float* tgtp = (const float*)d_in[1];
    float* dout = (float*)d_out;

    char* ws = (char*)d_ws;
    float* rad = (float*)ws;                                       // 64 KB
    const size_t partBytes = (size_t)NIMG * PBX * 512 * sizeof(float);  // 8.45 MB
    float* partial = (float*)(ws + 65536);
    float2* WpT = (float2*)(ws + 65536 + partBytes);
    const size_t perImg = (size_t)512 * 1024 * sizeof(float2);     // 4 MB / image
    size_t used = 65536 + partBytes;
    size_t avail = (ws_size > used) ? (ws_size - used) : 0;
    int chunk = (int)(avail / perImg);
    if (chunk > NIMG) chunk = NIMG;
    if (chunk < 1) chunk = 1;

    for (int base = 0; base < NIMG; base += chunk) {
        int c = (NIMG - base < chunk) ? (NIMG - base) : chunk;
        fft_rows<<<dim3(64, c), 512, 0, stream>>>(outp, tgtp, WpT, base);
        fft_cols_bin2<<<dim3(PBX, c), 512, 0, stream>>>(WpT, partial, base);
    }

    reduce_partials<<<NIMG, 512, 0, stream>>>(partial, rad);
    final_loss<<<1, 256, 0, stream>>>(rad, dout);
}